// Round 18
// baseline (87.162 us; speedup 1.0000x reference)
//
#include <hip/hip_runtime.h>
#include <hip/hip_bf16.h>

typedef __attribute__((ext_vector_type(8))) __bf16 bf16x8;
typedef __attribute__((ext_vector_type(4))) __bf16 bf16x4;
typedef __attribute__((ext_vector_type(4))) float f32x4;
typedef __attribute__((ext_vector_type(16))) float f32x16;

#define MFMA16(a, b, c) __builtin_amdgcn_mfma_f32_16x16x32_bf16((a), (b), (c), 0, 0, 0)
#define MFMA32(a, b, c) __builtin_amdgcn_mfma_f32_32x32x16_bf16((a), (b), (c), 0, 0, 0)

static constexpr int S_LEN = 4096;
static constexpr int DH = 128;
static constexpr int NR = 4 * S_LEN;  // B*S = 16384
// 1/sqrt(128) * log2(e): fold softmax scale AND exp->exp2 conversion into Q
static constexpr float QSCALE = 0.12752551286084110f;

__device__ inline bf16x8 pack8(float4 a, float4 b) {
  bf16x8 r;
  r[0] = (__bf16)a.x; r[1] = (__bf16)a.y; r[2] = (__bf16)a.z; r[3] = (__bf16)a.w;
  r[4] = (__bf16)b.x; r[5] = (__bf16)b.y; r[6] = (__bf16)b.z; r[7] = (__bf16)b.w;
  return r;
}

__device__ __forceinline__ float fexp2(float x) {
#if __has_builtin(__builtin_amdgcn_exp2f)
  return __builtin_amdgcn_exp2f(x);
#else
  return exp2f(x);
#endif
}

// Pack two f32 -> u32 of 2 bf16: a -> low 16 (elem 0), b -> high (elem 1).
// HW-verified in R10/R12/R14.
__device__ __forceinline__ unsigned packbf(float a, float b) {
  union { __bf16 h[2]; unsigned u; } t;
  t.h[0] = (__bf16)a;
  t.h[1] = (__bf16)b;
  return t.u;
}

typedef __attribute__((address_space(1))) const unsigned GU32;
typedef __attribute__((address_space(3))) unsigned LU32;
// async global->LDS, 16B per lane; LDS dest = wave-uniform base + lane*16
__device__ __forceinline__ void gl16(const void* g, void* s) {
  __builtin_amdgcn_global_load_lds((GU32*)g, (LU32*)s, 16, 0, 0);
}

// ---------------------------------------------------------------------------
// One prep kernel: conv K->bf16 | transpose V -> VT bf16 (kv bits 2,3
// SWAPPED: VTb[d][sigma(s)] = V^T[d][s], sigma = swap bits 2<->3) | prep w.
// R14-verified: sigma makes attn's PV consume P fully lane-locally.
// grid = 1024 + 2048 + 256 = 3328 blocks x 256 thr.
// ---------------------------------------------------------------------------
__global__ __launch_bounds__(256) void prep_all(
    const float* __restrict__ K, const float* __restrict__ V,
    const float* __restrict__ w1, const float* __restrict__ w2,
    __bf16* __restrict__ Kb, __bf16* __restrict__ VTb,
    __bf16* __restrict__ w1t, __bf16* __restrict__ w2t) {
  __shared__ float tile[32][33];
  const int bid = blockIdx.x;
  const int t = threadIdx.x;
  if (bid < 1024) {  // K f32 -> bf16 flat
    size_t i = ((size_t)bid * 256 + t) * 8;
    float4 a = *(const float4*)(K + i), b = *(const float4*)(K + i + 4);
    *(bf16x8*)(Kb + i) = pack8(a, b);
  } else if (bid < 3072) {  // V [B][S][128] -> VT [B][128][S] via 32x32 tiles
    const int bid2 = bid - 1024;
    const int b = bid2 >> 9, rem = bid2 & 511;
    const int s0 = (rem >> 2) * 32, d0 = (rem & 3) * 32;
    {
      int r = t >> 3, q = t & 7;
      float4 f = *(const float4*)(V + ((size_t)(b * S_LEN + s0 + r)) * DH + d0 + q * 4);
      tile[r][q * 4 + 0] = f.x; tile[r][q * 4 + 1] = f.y;
      tile[r][q * 4 + 2] = f.z; tile[r][q * 4 + 3] = f.w;
    }
    __syncthreads();
    {
      int dr = t >> 3, c2 = t & 7;
      bf16x4 u;
#pragma unroll
      for (int j = 0; j < 4; ++j) u[j] = (__bf16)tile[c2 * 4 + j][dr];
      // sigma: swap kv bits 2,3 == swap c2 bits 0,1 (4-group moves intact)
      int c2s = (c2 & 4) | ((c2 & 1) << 1) | ((c2 >> 1) & 1);
      *(bf16x4*)(VTb + ((size_t)(b * DH + d0 + dr)) * S_LEN + s0 + c2s * 4) = u;
    }
  } else {  // w1t[n][k]=bf16(w1[k][n]); w2t[n][k]=bf16(w2[k][n])
    int i = (bid - 3072) * 256 + t;
    {
      int n = i >> 7, kk = i & 127;
      w1t[i] = (__bf16)w1[kk * 512 + n];
    }
    {
      int n = i >> 9, kk = i & 511;
      w2t[i] = (__bf16)w2[kk * 128 + n];
    }
  }
}

// ---------------------------------------------------------------------------
// Flash attention, kv-split. 32x32 swapped MFMA (R6/R14-verified, VERBATIM
// R17 — benched 49.7 us, VGPR 120, no spill):
//   S^T = K · Q^T  -> lane owns q = l&31;  O^T = V^T · P^T.
// No-max softmax, per-lane lsum; sigma-permuted V -> lane-local P.
// Block = 4 waves (256 thr), 128 q-rows (32/wave). LDS 64 KB -> 2 blocks/CU.
// ---------------------------------------------------------------------------
template <int NSP>
__global__ __launch_bounds__(256, 2) void attn_fa(
    const float* __restrict__ Q, const __bf16* __restrict__ Kb,
    const __bf16* __restrict__ VTb, __bf16* __restrict__ Op,
    float* __restrict__ lbuf) {
  constexpr int NTT = (S_LEN / NSP) / 64;
  __shared__ __attribute__((aligned(16))) __bf16 kl[2][64 * 128];  // 32 KB
  __shared__ __attribute__((aligned(16))) __bf16 vt[2][128 * 64];  // 32 KB

  const int tid = threadIdx.x;
  const int w = tid >> 6, l = tid & 63;
  const int q5 = l & 31, hi = l >> 5;
  const int bid = blockIdx.x;
  const int split = bid % NSP;
  const int qt = (bid / NSP) % 32;
  const int b = bid / (NSP * 32);
  const int R = b * S_LEN + qt * 128 + w * 32 + q5;
  const int kv0 = split * (S_LEN / NSP);

  // Q^T B-frags (QSCALE folded): lane holds Q[q5-row][kc*16 + hi*8 + j]
  bf16x8 qf[8];
  {
    const float* qp = Q + (size_t)R * DH + hi * 8;
#pragma unroll
    for (int kc = 0; kc < 8; ++kc) {
      float4 f0 = *(const float4*)(qp + kc * 16);
      float4 f1 = *(const float4*)(qp + kc * 16 + 4);
      f0.x *= QSCALE; f0.y *= QSCALE; f0.z *= QSCALE; f0.w *= QSCALE;
      f1.x *= QSCALE; f1.y *= QSCALE; f1.z *= QSCALE; f1.w *= QSCALE;
      qf[kc] = pack8(f0, f1);
    }
  }

  f32x16 o[4];
#pragma unroll
  for (int db = 0; db < 4; ++db) o[db] = f32x16{};
  float lsum = 0.f;

  const __bf16* kbase = Kb + (size_t)b * S_LEN * DH;
  const __bf16* vbase = VTb + (size_t)b * DH * S_LEN;

  // R6-verified 4-wave staging: wave w stages K rows [w*16,w*16+16) and
  // VT rows [w*32,w*32+32). LDS image: slot[r][c] = src[r][c ^ ((r&7)<<3)].
#define STAGE(BUF, S_OFF)                                                      \
  {                                                                            \
    _Pragma("unroll") for (int i = 0; i < 4; ++i) {                            \
      int r = w * 16 + i * 4 + (l >> 4);                                       \
      gl16(kbase + (size_t)((S_OFF) + r) * DH + (((l & 15) * 8) ^ ((r & 7) << 3)), \
           &kl[BUF][(w * 16 + i * 4) * 128]);                                  \
    }                                                                          \
    _Pragma("unroll") for (int i = 0; i < 4; ++i) {                            \
      int d = w * 32 + i * 8 + (l >> 3);                                       \
      gl16(vbase + (size_t)d * S_LEN + (S_OFF) + (((l & 7) * 8) ^ ((d & 7) << 3)), \
           &vt[BUF][(w * 32 + i * 8) * 64]);                                   \
    }                                                                          \
  }

  STAGE(0, kv0);
  __syncthreads();  // implicit vmcnt(0) drain -> buffer 0 ready

  const int swz = (q5 & 7) << 3;

  int cur = 0;
  for (int t = 0; t < NTT; ++t) {
    if (t + 1 < NTT) STAGE(cur ^ 1, kv0 + (t + 1) * 64);  // prefetch in flight

    // ---- QK^T (S^T) + softmax + lane-local P assembly (R14-verified) ----
    bf16x8 pb[4];  // pb[kvb*2+kc2] feeds PV k-range 16*(2kvb+kc2)+8hi+j
#pragma unroll
    for (int kvb = 0; kvb < 2; ++kvb) {
      f32x16 acc = f32x16{};
      const int row = kvb * 32 + q5;  // row&7 == q5&7
#pragma unroll
      for (int kc = 0; kc < 8; ++kc) {
        bf16x8 kf = *(const bf16x8*)&kl[cur][(row * 128 + kc * 16 + hi * 8) ^ swz];
        acc = MFMA32(kf, qf[kc], acc);
      }
      // p = exp2(s); pack quads (4 consecutive kv) as 2x u32 of bf16 pairs.
      unsigned pk[4][2];
#pragma unroll
      for (int t4 = 0; t4 < 4; ++t4) {
        float e0 = fexp2(acc[4 * t4 + 0]), e1 = fexp2(acc[4 * t4 + 1]);
        float e2 = fexp2(acc[4 * t4 + 2]), e3 = fexp2(acc[4 * t4 + 3]);
        lsum += (e0 + e1) + (e2 + e3);
        pk[t4][0] = packbf(e0, e1);
        pk[t4][1] = packbf(e2, e3);
      }
#pragma unroll
      for (int kc2 = 0; kc2 < 2; ++kc2) {
        union { unsigned u[4]; bf16x8 v; } uu;
        uu.u[0] = pk[2 * kc2][0];
        uu.u[1] = pk[2 * kc2][1];
        uu.u[2] = pk[2 * kc2 + 1][0];
        uu.u[3] = pk[2 * kc2 + 1][1];
        pb[kvb * 2 + kc2] = uu.v;
      }
    }

    // ---- PV: O^T[d][q] += V^T·P^T (sigma in data) ----
#pragma unroll
    for (int db = 0; db < 4; ++db) {
      const int row = db * 32 + q5;  // row&7 == q5&7
#pragma unroll
      for (int kc = 0; kc < 4; ++kc) {
        bf16x8 vf = *(const bf16x8*)&vt[cur][(row * 64 + kc * 16 + hi * 8) ^ swz];
        o[db] = MFMA32(vf, pb[kc], o[db]);
      }
    }

    __syncthreads();  // drains prefetch (hidden under compute) + buffer swap
    cur ^= 1;
  }
#undef STAGE

  // ---- epilogue (R6-verified): full-row l, write O/l + l ----
  lsum += __shfl_xor(lsum, 32);
  const float inv = 1.f / lsum;
  __bf16* orow = Op + ((size_t)split * NR + R) * DH;
#pragma unroll
  for (int db = 0; db < 4; ++db)
#pragma unroll
    for (int t4 = 0; t4 < 4; ++t4) {
      bf16x4 pk;
#pragma unroll
      for (int qi = 0; qi < 4; ++qi) pk[qi] = (__bf16)(o[db][4 * t4 + qi] * inv);
      *(bf16x4*)(orow + db * 32 + t4 * 8 + hi * 4) = pk;
    }
  if (hi == 0) lbuf[(size_t)split * NR + R] = lsum;
}

// ---------------------------------------------------------------------------
// Fused: combine kv-splits + LN1 (LDS only) + FFN + LN2 -> Out.
// 32 rows per block (2 x 16-row groups, R17-verified). NEW: residual xr in
// bf16 (LDS ~30 KB -> 4 blocks/CU) + GEMM2 loop interchange (2 indep chains).
// ---------------------------------------------------------------------------
template <int NSP>
__global__ __launch_bounds__(256) void ffn_fused(
    const __bf16* __restrict__ Op, const float* __restrict__ lbuf,
    const float* __restrict__ g1, const float* __restrict__ be1,
    const __bf16* __restrict__ w1t, const __bf16* __restrict__ w2t,
    const float* __restrict__ b1, const float* __restrict__ b2,
    const float* __restrict__ g2, const float* __restrict__ be2,
    float* __restrict__ Out) {
  __shared__ __attribute__((aligned(16))) __bf16 xl[2][16 * 128];   // 8 KB
  __shared__ __attribute__((aligned(16))) __bf16 xr[2][16][136];    // 8.5 KB
  __shared__ __attribute__((aligned(16))) __bf16 hl[16 * 512];      // 16 KB
  __shared__ float part[4][16][2];

  const int tid = threadIdx.x;
  const int w = tid >> 6, l = tid & 63, lg = l >> 4, lc = l & 15;
  const int row0 = blockIdx.x * 32;

  // ---- phase 1: combine splits + LayerNorm1 for BOTH 16-row groups ----
#pragma unroll
  for (int g = 0; g < 2; ++g) {
    const int prow = tid >> 4, pc8 = tid & 15;
    const int R = row0 + g * 16 + prow;
    float v[8] = {0.f, 0.f, 0.f, 0.f, 0.f, 0.f, 0.f, 0.f};
    float den = 0.f;
#pragma unroll
    for (int s = 0; s < NSP; ++s) {
      float ls = lbuf[(size_t)s * NR + R];
      den += ls;
      bf16x8 p = *(const bf16x8*)(Op + ((size_t)s * NR + R) * DH + pc8 * 8);
#pragma unroll
      for (int j = 0; j < 8; ++j) v[j] += ls * (float)p[j];
    }
    float inv = 1.f / den;
    float sm = 0.f, sq = 0.f;
#pragma unroll
    for (int j = 0; j < 8; ++j) {
      v[j] *= inv;
      sm += v[j];
      sq += v[j] * v[j];
    }
#pragma unroll
    for (int d = 1; d < 16; d <<= 1) {
      sm += __shfl_xor(sm, d);
      sq += __shfl_xor(sq, d);
    }
    float mu = sm * (1.f / 128.f);
    float var = sq * (1.f / 128.f) - mu * mu;
    float rs = rsqrtf(var + 1e-5f);
    float4 ga = *(const float4*)(g1 + pc8 * 8), gb = *(const float4*)(g1 + pc8 * 8 + 4);
    float4 ba = *(const float4*)(be1 + pc8 * 8), bb = *(const float4*)(be1 + pc8 * 8 + 4);
    float gv[8] = {ga.x, ga.y, ga.z, ga.w, gb.x, gb.y, gb.z, gb.w};
    float bv[8] = {ba.x, ba.y, ba.z, ba.w, bb.x, bb.y, bb.z, bb.w};
    bf16x8 xb;
#pragma unroll
    for (int j = 0; j < 8; ++j) {
      float xo = (v[j] - mu) * rs * gv[j] + bv[j];
      xb[j] = (__bf16)xo;
    }
    *(bf16x8*)&xl[g][(prow * 128 + pc8 * 8) ^ ((prow & 7) << 3)] = xb;
    *(bf16x8*)&xr[g][prow][pc8 * 8] = xb;  // bf16 residual (LN2 tolerant)
  }
  __syncthreads();

  // ---- per group: GEMM1 -> hl -> GEMM2 + residual + LN2 -> Out ----
  for (int g = 0; g < 2; ++g) {
    // GEMM1 + bias + relu -> hl
    bf16x8 xf[4];
    const int m = lc;
#pragma unroll
    for (int kc = 0; kc < 4; ++kc)
      xf[kc] = *(const bf16x8*)&xl[g][(m * 128 + kc * 32 + lg * 8) ^ ((m & 7) << 3)];

#pragma unroll
    for (int nb = 0; nb < 8; ++nb) {
      int n0 = w * 128 + nb * 16 + lc;
      const __bf16* wp = w1t + (size_t)n0 * 128 + lg * 8;
      f32x4 acc = (f32x4){0.f, 0.f, 0.f, 0.f};
#pragma unroll
      for (int kc = 0; kc < 4; ++kc)
        acc = MFMA16(xf[kc], *(const bf16x8*)(wp + kc * 32), acc);
      float bias = b1[n0];
#pragma unroll
      for (int r = 0; r < 4; ++r) {
        int rr = lg * 4 + r;
        hl[rr * 512 + (n0 ^ (lg << 4))] = (__bf16)fmaxf(acc[r] + bias, 0.f);
      }
    }
    __syncthreads();

    // GEMM2 (K=512) + bias + residual + LN2 — kc outer, 2 indep acc chains
    const int col0 = w * 32 + lc;
    const __bf16* wp2a = w2t + (size_t)col0 * 512 + lg * 8;
    const __bf16* wp2b = w2t + (size_t)(col0 + 16) * 512 + lg * 8;
    f32x4 oo[2];
    oo[0] = (f32x4){0.f, 0.f, 0.f, 0.f};
    oo[1] = (f32x4){0.f, 0.f, 0.f, 0.f};
#pragma unroll
    for (int kc = 0; kc < 16; ++kc) {
      bf16x8 ha = *(const bf16x8*)&hl[lc * 512 + ((kc * 32 + lg * 8) ^ ((lc >> 2) << 4))];
      oo[0] = MFMA16(ha, *(const bf16x8*)(wp2a + kc * 32), oo[0]);
      oo[1] = MFMA16(ha, *(const bf16x8*)(wp2b + kc * 32), oo[1]);
    }

    float b2v[2] = {b2[col0], b2[col0 + 16]};
    float g2v[2] = {g2[col0], g2[col0 + 16]};
    float be2v[2] = {be2[col0], be2[col0 + 16]};
    float sum[4] = {0.f, 0.f, 0.f, 0.f}, sq[4] = {0.f, 0.f, 0.f, 0.f};
#pragma unroll
    for (int nb2 = 0; nb2 < 2; ++nb2)
#pragma unroll
      for (int r = 0; r < 4; ++r) {
        int rr = lg * 4 + r;
        float xv = (float)xr[g][rr][col0 + nb2 * 16];
        float tv = oo[nb2][r] + b2v[nb2] + xv;
        oo[nb2][r] = tv;
        sum[r] += tv;
        sq[r] += tv * tv;
      }
#pragma unroll
    for (int r = 0; r < 4; ++r) {
#pragma unroll
      for (int d = 1; d < 16; d <<= 1) {
        sum[r] += __shfl_xor(sum[r], d);
        sq[r] += __shfl_xor(sq[r], d);
      }
      if (lc == 0) {
        part[w][lg * 4 + r][0] = sum[r];
        part[w][lg * 4 + r][1] = sq[r];
      }
    }
    __syncthreads();

#pragma unroll
    for (int r = 0; r < 4; ++r) {
      int rr = lg * 4 + r;
      float S = 0.f, Qq = 0.f;
#pragma unroll
      for (int ww = 0; ww < 4; ++ww) {
        S += part[ww][rr][0];
        Qq += part[ww][rr][1];
      }
      float mu = S * (1.f / 128.f);
      float var = Qq * (1.f / 128.f) - mu * mu;
      float rs = rsqrtf(var + 1e-5f);
#pragma unroll
      for (int nb2 = 0; nb2 < 2; ++nb2)
        Out[(size_t)(row0 + g * 16 + rr) * DH + col0 + nb2 * 16] =
            (oo[nb2][r] - mu) * rs * g2v[nb2] + be2v[nb2];
    }
    __syncthreads();  // hl/part free for next group
  }
}

// ---------------------------------------------------------------------------
extern "C" void kernel_launch(void* const* d_in, const int* in_sizes, int n_in,
                              void* d_out, int out_size, void* d_ws, size_t ws_size,
                              hipStream_t stream) {
  const float* Q = (const float*)d_in[0];
  const float* K = (const float*)d_in[1];
  const float* V = (const float*)d_in[2];
  const float* w1 = (const float*)d_in[3];
  const float* b1 = (const float*)d_in[4];
  const float* w2 = (const float*)d_in[5];
  const float* b2 = (const float*)d_in[6];
  const float* g1 = (const float*)d_in[7];
  const float* be1 = (const float*)d_in[8];
  const float* g2 = (const float*)d_in[9];
  const float* be2 = (const float*)d_in[10];
  float* Out = (float*)d_out;

  char* p = (char*)d_ws;
  __bf16* w1t = (__bf16*)p;  p += 512 * 128 * 2;
  __bf16* w2t = (__bf16*)p;  p += 128 * 512 * 2;
  __bf16* Kb  = (__bf16*)p;  p += (size_t)NR * DH * 2;
  __bf16* VTb = (__bf16*)p;  p += (size_t)NR * DH * 2;
  float* lbuf = (float*)p;   p += (size_t)4 * NR * 4;
  __bf16* Op  = (__bf16*)p;  // 4 * NR * DH * 2 = 16 MB

  prep_all<<<3328, 256, 0, stream>>>(K, V, w1, w2, Kb, VTb, w1t, w2t);
  // NSP=4: grid 512 = exactly 2 blocks/CU on 256 CUs, one dispatch round.
  attn_fa<4><<<4 * 32 * 4, 256, 0, stream>>>(Q, Kb, VTb, Op, lbuf);
  ffn_fused<4><<<NR / 32, 256, 0, stream>>>(Op, lbuf, g1, be1, w1t, w2t, b1,
                                            b2, g2, be2, Out);
}

// Round 19
// 86.478 us; speedup vs baseline: 1.0079x; 1.0079x over previous
//
#include <hip/hip_runtime.h>
#include <hip/hip_bf16.h>

typedef __attribute__((ext_vector_type(8))) __bf16 bf16x8;
typedef __attribute__((ext_vector_type(4))) __bf16 bf16x4;
typedef __attribute__((ext_vector_type(4))) float f32x4;
typedef __attribute__((ext_vector_type(16))) float f32x16;

#define MFMA16(a, b, c) __builtin_amdgcn_mfma_f32_16x16x32_bf16((a), (b), (c), 0, 0, 0)
#define MFMA32(a, b, c) __builtin_amdgcn_mfma_f32_32x32x16_bf16((a), (b), (c), 0, 0, 0)

static constexpr int S_LEN = 4096;
static constexpr int DH = 128;
static constexpr int NR = 4 * S_LEN;  // B*S = 16384
// 1/sqrt(128) * log2(e): fold softmax scale AND exp->exp2 conversion into Q
static constexpr float QSCALE = 0.12752551286084110f;

__device__ inline bf16x8 pack8(float4 a, float4 b) {
  bf16x8 r;
  r[0] = (__bf16)a.x; r[1] = (__bf16)a.y; r[2] = (__bf16)a.z; r[3] = (__bf16)a.w;
  r[4] = (__bf16)b.x; r[5] = (__bf16)b.y; r[6] = (__bf16)b.z; r[7] = (__bf16)b.w;
  return r;
}

__device__ __forceinline__ float fexp2(float x) {
#if __has_builtin(__builtin_amdgcn_exp2f)
  return __builtin_amdgcn_exp2f(x);
#else
  return exp2f(x);
#endif
}

// Pack two f32 -> u32 of 2 bf16: a -> low 16 (elem 0), b -> high (elem 1).
// HW-verified in R10/R12/R14.
__device__ __forceinline__ unsigned packbf(float a, float b) {
  union { __bf16 h[2]; unsigned u; } t;
  t.h[0] = (__bf16)a;
  t.h[1] = (__bf16)b;
  return t.u;
}

typedef __attribute__((address_space(1))) const unsigned GU32;
typedef __attribute__((address_space(3))) unsigned LU32;
// async global->LDS, 16B per lane; LDS dest = wave-uniform base + lane*16
__device__ __forceinline__ void gl16(const void* g, void* s) {
  __builtin_amdgcn_global_load_lds((GU32*)g, (LU32*)s, 16, 0, 0);
}

// ---------------------------------------------------------------------------
// One prep kernel: conv K->bf16 | transpose V -> VT bf16 (sigma: kv bits 2,3
// swapped — R14-verified, makes attn PV lane-local) | conv Q->bf16*QSCALE |
// prep w.  grid = 1024 + 2048 + 1024 + 256 = 4352 blocks x 256 thr.
// ---------------------------------------------------------------------------
__global__ __launch_bounds__(256) void prep_all(
    const float* __restrict__ K, const float* __restrict__ V,
    const float* __restrict__ Q, const float* __restrict__ w1,
    const float* __restrict__ w2, __bf16* __restrict__ Kb,
    __bf16* __restrict__ VTb, __bf16* __restrict__ Qb,
    __bf16* __restrict__ w1t, __bf16* __restrict__ w2t) {
  __shared__ float tile[32][33];
  const int bid = blockIdx.x;
  const int t = threadIdx.x;
  if (bid < 1024) {  // K f32 -> bf16 flat
    size_t i = ((size_t)bid * 256 + t) * 8;
    float4 a = *(const float4*)(K + i), b = *(const float4*)(K + i + 4);
    *(bf16x8*)(Kb + i) = pack8(a, b);
  } else if (bid < 3072) {  // V [B][S][128] -> VT [B][128][S] via 32x32 tiles
    const int bid2 = bid - 1024;
    const int b = bid2 >> 9, rem = bid2 & 511;
    const int s0 = (rem >> 2) * 32, d0 = (rem & 3) * 32;
    {
      int r = t >> 3, q = t & 7;
      float4 f = *(const float4*)(V + ((size_t)(b * S_LEN + s0 + r)) * DH + d0 + q * 4);
      tile[r][q * 4 + 0] = f.x; tile[r][q * 4 + 1] = f.y;
      tile[r][q * 4 + 2] = f.z; tile[r][q * 4 + 3] = f.w;
    }
    __syncthreads();
    {
      int dr = t >> 3, c2 = t & 7;
      bf16x4 u;
#pragma unroll
      for (int j = 0; j < 4; ++j) u[j] = (__bf16)tile[c2 * 4 + j][dr];
      // sigma: swap kv bits 2,3 == swap c2 bits 0,1 (4-group moves intact)
      int c2s = (c2 & 4) | ((c2 & 1) << 1) | ((c2 >> 1) & 1);
      *(bf16x4*)(VTb + ((size_t)(b * DH + d0 + dr)) * S_LEN + s0 + c2s * 4) = u;
    }
  } else if (bid < 4096) {  // Q f32 -> bf16 * QSCALE flat (same math as R17)
    size_t i = ((size_t)(bid - 3072) * 256 + t) * 8;
    float4 a = *(const float4*)(Q + i), b = *(const float4*)(Q + i + 4);
    a.x *= QSCALE; a.y *= QSCALE; a.z *= QSCALE; a.w *= QSCALE;
    b.x *= QSCALE; b.y *= QSCALE; b.z *= QSCALE; b.w *= QSCALE;
    *(bf16x8*)(Qb + i) = pack8(a, b);
  } else {  // w1t[n][k]=bf16(w1[k][n]); w2t[n][k]=bf16(w2[k][n])
    int i = (bid - 4096) * 256 + t;
    {
      int n = i >> 7, kk = i & 127;
      w1t[i] = (__bf16)w1[kk * 512 + n];
    }
    {
      int n = i >> 9, kk = i & 511;
      w2t[i] = (__bf16)w2[kk * 128 + n];
    }
  }
}

// ---------------------------------------------------------------------------
// Flash attention, kv-split. 32x32 swapped MFMA (R6/R14/R17-verified):
//   S^T = K · Q^T  -> lane owns q = l&31;  O^T = V^T · P^T.
// No-max softmax, per-lane lsum; sigma-permuted V -> lane-local P.
// Q now pre-converted (bf16, QSCALE folded) -> 8x16B prologue loads.
// Block = 4 waves (256 thr), 128 q-rows (32/wave). LDS 64 KB -> 2 blocks/CU.
// ---------------------------------------------------------------------------
template <int NSP>
__global__ __launch_bounds__(256, 2) void attn_fa(
    const __bf16* __restrict__ Qb, const __bf16* __restrict__ Kb,
    const __bf16* __restrict__ VTb, __bf16* __restrict__ Op,
    float* __restrict__ lbuf) {
  constexpr int NTT = (S_LEN / NSP) / 64;
  __shared__ __attribute__((aligned(16))) __bf16 kl[2][64 * 128];  // 32 KB
  __shared__ __attribute__((aligned(16))) __bf16 vt[2][128 * 64];  // 32 KB

  const int tid = threadIdx.x;
  const int w = tid >> 6, l = tid & 63;
  const int q5 = l & 31, hi = l >> 5;
  const int bid = blockIdx.x;
  const int split = bid % NSP;
  const int qt = (bid / NSP) % 32;
  const int b = bid / (NSP * 32);
  const int R = b * S_LEN + qt * 128 + w * 32 + q5;
  const int kv0 = split * (S_LEN / NSP);

  // Q^T B-frags: lane holds Q[q5-row][kc*16 + hi*8 + j] (pre-scaled bf16)
  bf16x8 qf[8];
  {
    const __bf16* qp = Qb + (size_t)R * DH + hi * 8;
#pragma unroll
    for (int kc = 0; kc < 8; ++kc) qf[kc] = *(const bf16x8*)(qp + kc * 16);
  }

  f32x16 o[4];
#pragma unroll
  for (int db = 0; db < 4; ++db) o[db] = f32x16{};
  float lsum = 0.f;

  const __bf16* kbase = Kb + (size_t)b * S_LEN * DH;
  const __bf16* vbase = VTb + (size_t)b * DH * S_LEN;

  // R6-verified 4-wave staging: wave w stages K rows [w*16,w*16+16) and
  // VT rows [w*32,w*32+32). LDS image: slot[r][c] = src[r][c ^ ((r&7)<<3)].
#define STAGE(BUF, S_OFF)                                                      \
  {                                                                            \
    _Pragma("unroll") for (int i = 0; i < 4; ++i) {                            \
      int r = w * 16 + i * 4 + (l >> 4);                                       \
      gl16(kbase + (size_t)((S_OFF) + r) * DH + (((l & 15) * 8) ^ ((r & 7) << 3)), \
           &kl[BUF][(w * 16 + i * 4) * 128]);                                  \
    }                                                                          \
    _Pragma("unroll") for (int i = 0; i < 4; ++i) {                            \
      int d = w * 32 + i * 8 + (l >> 3);                                       \
      gl16(vbase + (size_t)d * S_LEN + (S_OFF) + (((l & 7) * 8) ^ ((d & 7) << 3)), \
           &vt[BUF][(w * 32 + i * 8) * 64]);                                   \
    }                                                                          \
  }

  STAGE(0, kv0);
  __syncthreads();  // implicit vmcnt(0) drain -> buffer 0 ready

  const int swz = (q5 & 7) << 3;

  int cur = 0;
  for (int t = 0; t < NTT; ++t) {
    if (t + 1 < NTT) STAGE(cur ^ 1, kv0 + (t + 1) * 64);  // prefetch in flight

    // ---- QK^T (S^T) + softmax + lane-local P assembly (R14-verified) ----
    bf16x8 pb[4];  // pb[kvb*2+kc2] feeds PV k-range 16*(2kvb+kc2)+8hi+j
#pragma unroll
    for (int kvb = 0; kvb < 2; ++kvb) {
      f32x16 acc = f32x16{};
      const int row = kvb * 32 + q5;  // row&7 == q5&7
#pragma unroll
      for (int kc = 0; kc < 8; ++kc) {
        bf16x8 kf = *(const bf16x8*)&kl[cur][(row * 128 + kc * 16 + hi * 8) ^ swz];
        acc = MFMA32(kf, qf[kc], acc);
      }
      // p = exp2(s); pack quads (4 consecutive kv) as 2x u32 of bf16 pairs.
      unsigned pk[4][2];
#pragma unroll
      for (int t4 = 0; t4 < 4; ++t4) {
        float e0 = fexp2(acc[4 * t4 + 0]), e1 = fexp2(acc[4 * t4 + 1]);
        float e2 = fexp2(acc[4 * t4 + 2]), e3 = fexp2(acc[4 * t4 + 3]);
        lsum += (e0 + e1) + (e2 + e3);
        pk[t4][0] = packbf(e0, e1);
        pk[t4][1] = packbf(e2, e3);
      }
#pragma unroll
      for (int kc2 = 0; kc2 < 2; ++kc2) {
        union { unsigned u[4]; bf16x8 v; } uu;
        uu.u[0] = pk[2 * kc2][0];
        uu.u[1] = pk[2 * kc2][1];
        uu.u[2] = pk[2 * kc2 + 1][0];
        uu.u[3] = pk[2 * kc2 + 1][1];
        pb[kvb * 2 + kc2] = uu.v;
      }
    }

    // ---- PV: O^T[d][q] += V^T·P^T (sigma in data) ----
#pragma unroll
    for (int db = 0; db < 4; ++db) {
      const int row = db * 32 + q5;  // row&7 == q5&7
#pragma unroll
      for (int kc = 0; kc < 4; ++kc) {
        bf16x8 vf = *(const bf16x8*)&vt[cur][(row * 64 + kc * 16 + hi * 8) ^ swz];
        o[db] = MFMA32(vf, pb[kc], o[db]);
      }
    }

    __syncthreads();  // drains prefetch (hidden under compute) + buffer swap
    cur ^= 1;
  }
#undef STAGE

  // ---- epilogue (R6-verified): full-row l, write O/l + l ----
  lsum += __shfl_xor(lsum, 32);
  const float inv = 1.f / lsum;
  __bf16* orow = Op + ((size_t)split * NR + R) * DH;
#pragma unroll
  for (int db = 0; db < 4; ++db)
#pragma unroll
    for (int t4 = 0; t4 < 4; ++t4) {
      bf16x4 pk;
#pragma unroll
      for (int qi = 0; qi < 4; ++qi) pk[qi] = (__bf16)(o[db][4 * t4 + qi] * inv);
      *(bf16x4*)(orow + db * 32 + t4 * 8 + hi * 4) = pk;
    }
  if (hi == 0) lbuf[(size_t)split * NR + R] = lsum;
}

// ---------------------------------------------------------------------------
// Fused: combine kv-splits + LN1 (LDS only) + FFN + LN2 -> Out.
// 32 rows per block (2 x 16-row groups) — R17-verified form (f32 residual).
// ---------------------------------------------------------------------------
template <int NSP>
__global__ __launch_bounds__(256) void ffn_fused(
    const __bf16* __restrict__ Op, const float* __restrict__ lbuf,
    const float* __restrict__ g1, const float* __restrict__ be1,
    const __bf16* __restrict__ w1t, const __bf16* __restrict__ w2t,
    const float* __restrict__ b1, const float* __restrict__ b2,
    const float* __restrict__ g2, const float* __restrict__ be2,
    float* __restrict__ Out) {
  __shared__ __attribute__((aligned(16))) __bf16 xl[2][16 * 128];  // 8 KB
  __shared__ float xr[2][16][132];                                 // 16.5 KB
  __shared__ __attribute__((aligned(16))) __bf16 hl[16 * 512];     // 16 KB
  __shared__ float part[4][16][2];

  const int tid = threadIdx.x;
  const int w = tid >> 6, l = tid & 63, lg = l >> 4, lc = l & 15;
  const int row0 = blockIdx.x * 32;

  // ---- phase 1: combine splits + LayerNorm1 for BOTH 16-row groups ----
#pragma unroll
  for (int g = 0; g < 2; ++g) {
    const int prow = tid >> 4, pc8 = tid & 15;
    const int R = row0 + g * 16 + prow;
    float v[8] = {0.f, 0.f, 0.f, 0.f, 0.f, 0.f, 0.f, 0.f};
    float den = 0.f;
#pragma unroll
    for (int s = 0; s < NSP; ++s) {
      float ls = lbuf[(size_t)s * NR + R];
      den += ls;
      bf16x8 p = *(const bf16x8*)(Op + ((size_t)s * NR + R) * DH + pc8 * 8);
#pragma unroll
      for (int j = 0; j < 8; ++j) v[j] += ls * (float)p[j];
    }
    float inv = 1.f / den;
    float sm = 0.f, sq = 0.f;
#pragma unroll
    for (int j = 0; j < 8; ++j) {
      v[j] *= inv;
      sm += v[j];
      sq += v[j] * v[j];
    }
#pragma unroll
    for (int d = 1; d < 16; d <<= 1) {
      sm += __shfl_xor(sm, d);
      sq += __shfl_xor(sq, d);
    }
    float mu = sm * (1.f / 128.f);
    float var = sq * (1.f / 128.f) - mu * mu;
    float rs = rsqrtf(var + 1e-5f);
    float4 ga = *(const float4*)(g1 + pc8 * 8), gb = *(const float4*)(g1 + pc8 * 8 + 4);
    float4 ba = *(const float4*)(be1 + pc8 * 8), bb = *(const float4*)(be1 + pc8 * 8 + 4);
    float gv[8] = {ga.x, ga.y, ga.z, ga.w, gb.x, gb.y, gb.z, gb.w};
    float bv[8] = {ba.x, ba.y, ba.z, ba.w, bb.x, bb.y, bb.z, bb.w};
    bf16x8 xb;
    float xo[8];
#pragma unroll
    for (int j = 0; j < 8; ++j) {
      xo[j] = (v[j] - mu) * rs * gv[j] + bv[j];
      xb[j] = (__bf16)xo[j];
    }
    *(bf16x8*)&xl[g][(prow * 128 + pc8 * 8) ^ ((prow & 7) << 3)] = xb;
    *(float4*)&xr[g][prow][pc8 * 8] = make_float4(xo[0], xo[1], xo[2], xo[3]);
    *(float4*)&xr[g][prow][pc8 * 8 + 4] = make_float4(xo[4], xo[5], xo[6], xo[7]);
  }
  __syncthreads();

  // ---- per group: GEMM1 -> hl -> GEMM2 + residual + LN2 -> Out ----
  for (int g = 0; g < 2; ++g) {
    // GEMM1 + bias + relu -> hl
    bf16x8 xf[4];
    const int m = lc;
#pragma unroll
    for (int kc = 0; kc < 4; ++kc)
      xf[kc] = *(const bf16x8*)&xl[g][(m * 128 + kc * 32 + lg * 8) ^ ((m & 7) << 3)];

#pragma unroll
    for (int nb = 0; nb < 8; ++nb) {
      int n0 = w * 128 + nb * 16 + lc;
      const __bf16* wp = w1t + (size_t)n0 * 128 + lg * 8;
      f32x4 acc = (f32x4){0.f, 0.f, 0.f, 0.f};
#pragma unroll
      for (int kc = 0; kc < 4; ++kc)
        acc = MFMA16(xf[kc], *(const bf16x8*)(wp + kc * 32), acc);
      float bias = b1[n0];
#pragma unroll
      for (int r = 0; r < 4; ++r) {
        int rr = lg * 4 + r;
        hl[rr * 512 + (n0 ^ (lg << 4))] = (__bf16)fmaxf(acc[r] + bias, 0.f);
      }
    }
    __syncthreads();

    // GEMM2 (K=512) + bias + residual + LN2
    const int col0 = w * 32 + lc;
    f32x4 oo[2];
#pragma unroll
    for (int nb2 = 0; nb2 < 2; ++nb2) {
      int d0 = col0 + nb2 * 16;
      const __bf16* wp2 = w2t + (size_t)d0 * 512 + lg * 8;
      f32x4 acc = (f32x4){0.f, 0.f, 0.f, 0.f};
#pragma unroll
      for (int kc = 0; kc < 16; ++kc) {
        bf16x8 ha = *(const bf16x8*)&hl[lc * 512 + ((kc * 32 + lg * 8) ^ ((lc >> 2) << 4))];
        acc = MFMA16(ha, *(const bf16x8*)(wp2 + kc * 32), acc);
      }
      oo[nb2] = acc;
    }

    float b2v[2] = {b2[col0], b2[col0 + 16]};
    float g2v[2] = {g2[col0], g2[col0 + 16]};
    float be2v[2] = {be2[col0], be2[col0 + 16]};
    float sum[4] = {0.f, 0.f, 0.f, 0.f}, sq[4] = {0.f, 0.f, 0.f, 0.f};
#pragma unroll
    for (int nb2 = 0; nb2 < 2; ++nb2)
#pragma unroll
      for (int r = 0; r < 4; ++r) {
        int rr = lg * 4 + r;
        float xv = xr[g][rr][col0 + nb2 * 16];
        float tv = oo[nb2][r] + b2v[nb2] + xv;
        oo[nb2][r] = tv;
        sum[r] += tv;
        sq[r] += tv * tv;
      }
#pragma unroll
    for (int r = 0; r < 4; ++r) {
#pragma unroll
      for (int d = 1; d < 16; d <<= 1) {
        sum[r] += __shfl_xor(sum[r], d);
        sq[r] += __shfl_xor(sq[r], d);
      }
      if (lc == 0) {
        part[w][lg * 4 + r][0] = sum[r];
        part[w][lg * 4 + r][1] = sq[r];
      }
    }
    __syncthreads();

#pragma unroll
    for (int r = 0; r < 4; ++r) {
      int rr = lg * 4 + r;
      float S = 0.f, Qq = 0.f;
#pragma unroll
      for (int ww = 0; ww < 4; ++ww) {
        S += part[ww][rr][0];
        Qq += part[ww][rr][1];
      }
      float mu = S * (1.f / 128.f);
      float var = Qq * (1.f / 128.f) - mu * mu;
      float rs = rsqrtf(var + 1e-5f);
#pragma unroll
      for (int nb2 = 0; nb2 < 2; ++nb2)
        Out[(size_t)(row0 + g * 16 + rr) * DH + col0 + nb2 * 16] =
            (oo[nb2][r] - mu) * rs * g2v[nb2] + be2v[nb2];
    }
    __syncthreads();  // hl/part free for next group
  }
}

// ---------------------------------------------------------------------------
extern "C" void kernel_launch(void* const* d_in, const int* in_sizes, int n_in,
                              void* d_out, int out_size, void* d_ws, size_t ws_size,
                              hipStream_t stream) {
  const float* Q = (const float*)d_in[0];
  const float* K = (const float*)d_in[1];
  const float* V = (const float*)d_in[2];
  const float* w1 = (const float*)d_in[3];
  const float* b1 = (const float*)d_in[4];
  const float* w2 = (const float*)d_in[5];
  const float* b2 = (const float*)d_in[6];
  const float* g1 = (const float*)d_in[7];
  const float* be1 = (const float*)d_in[8];
  const float* g2 = (const float*)d_in[9];
  const float* be2 = (const float*)d_in[10];
  float* Out = (float*)d_out;

  char* p = (char*)d_ws;
  __bf16* w1t = (__bf16*)p;  p += 512 * 128 * 2;
  __bf16* w2t = (__bf16*)p;  p += 128 * 512 * 2;
  __bf16* Kb  = (__bf16*)p;  p += (size_t)NR * DH * 2;
  __bf16* VTb = (__bf16*)p;  p += (size_t)NR * DH * 2;
  __bf16* Qb  = (__bf16*)p;  p += (size_t)NR * DH * 2;
  float* lbuf = (float*)p;   p += (size_t)4 * NR * 4;
  __bf16* Op  = (__bf16*)p;  // 4 * NR * DH * 2 = 16 MB

  prep_all<<<4352, 256, 0, stream>>>(K, V, Q, w1, w2, Kb, VTb, Qb, w1t, w2t);
  // NSP=4: grid 512 = exactly 2 blocks/CU on 256 CUs, one dispatch round.
  attn_fa<4><<<4 * 32 * 4, 256, 0, stream>>>(Qb, Kb, VTb, Op, lbuf);
  ffn_fused<4><<<NR / 32, 256, 0, stream>>>(Op, lbuf, g1, be1, w1t, w2t, b1,
                                            b2, g2, be2, Out);
}

// Round 20
// 86.267 us; speedup vs baseline: 1.0104x; 1.0024x over previous
//
#include <hip/hip_runtime.h>
#include <hip/hip_bf16.h>

typedef __attribute__((ext_vector_type(8))) __bf16 bf16x8;
typedef __attribute__((ext_vector_type(4))) __bf16 bf16x4;
typedef __attribute__((ext_vector_type(4))) float f32x4;
typedef __attribute__((ext_vector_type(16))) float f32x16;

#define MFMA16(a, b, c) __builtin_amdgcn_mfma_f32_16x16x32_bf16((a), (b), (c), 0, 0, 0)
#define MFMA32(a, b, c) __builtin_amdgcn_mfma_f32_32x32x16_bf16((a), (b), (c), 0, 0, 0)

static constexpr int S_LEN = 4096;
static constexpr int DH = 128;
static constexpr int NR = 4 * S_LEN;  // B*S = 16384
// 1/sqrt(128) * log2(e): fold softmax scale AND exp->exp2 conversion into Q
static constexpr float QSCALE = 0.12752551286084110f;

__device__ inline bf16x8 pack8(float4 a, float4 b) {
  bf16x8 r;
  r[0] = (__bf16)a.x; r[1] = (__bf16)a.y; r[2] = (__bf16)a.z; r[3] = (__bf16)a.w;
  r[4] = (__bf16)b.x; r[5] = (__bf16)b.y; r[6] = (__bf16)b.z; r[7] = (__bf16)b.w;
  return r;
}

__device__ __forceinline__ float fexp2(float x) {
#if __has_builtin(__builtin_amdgcn_exp2f)
  return __builtin_amdgcn_exp2f(x);
#else
  return exp2f(x);
#endif
}

// Pack two f32 -> u32 of 2 bf16: a -> low 16 (elem 0), b -> high (elem 1).
// HW-verified in R10/R12/R14.
__device__ __forceinline__ unsigned packbf(float a, float b) {
  union { __bf16 h[2]; unsigned u; } t;
  t.h[0] = (__bf16)a;
  t.h[1] = (__bf16)b;
  return t.u;
}

typedef __attribute__((address_space(1))) const unsigned GU32;
typedef __attribute__((address_space(3))) unsigned LU32;
// async global->LDS, 16B per lane; LDS dest = wave-uniform base + lane*16
__device__ __forceinline__ void gl16(const void* g, void* s) {
  __builtin_amdgcn_global_load_lds((GU32*)g, (LU32*)s, 16, 0, 0);
}

// ---------------------------------------------------------------------------
// One prep kernel: conv K->bf16 | transpose V -> VT bf16 (sigma: kv bits 2,3
// swapped — R14-verified) | conv Q->bf16*QSCALE | transpose w1,w2 via LDS
// tiles (coalesced — replaces scattered per-element gather).
// grid = 1024 + 2048 + 1024 + 128 = 4224 blocks x 256 thr.
// ---------------------------------------------------------------------------
__global__ __launch_bounds__(256) void prep_all(
    const float* __restrict__ K, const float* __restrict__ V,
    const float* __restrict__ Q, const float* __restrict__ w1,
    const float* __restrict__ w2, __bf16* __restrict__ Kb,
    __bf16* __restrict__ VTb, __bf16* __restrict__ Qb,
    __bf16* __restrict__ w1t, __bf16* __restrict__ w2t) {
  __shared__ float tile[32][33];
  const int bid = blockIdx.x;
  const int t = threadIdx.x;
  if (bid < 1024) {  // K f32 -> bf16 flat
    size_t i = ((size_t)bid * 256 + t) * 8;
    float4 a = *(const float4*)(K + i), b = *(const float4*)(K + i + 4);
    *(bf16x8*)(Kb + i) = pack8(a, b);
  } else if (bid < 3072) {  // V [B][S][128] -> VT [B][128][S] via 32x32 tiles
    const int bid2 = bid - 1024;
    const int b = bid2 >> 9, rem = bid2 & 511;
    const int s0 = (rem >> 2) * 32, d0 = (rem & 3) * 32;
    {
      int r = t >> 3, q = t & 7;
      float4 f = *(const float4*)(V + ((size_t)(b * S_LEN + s0 + r)) * DH + d0 + q * 4);
      tile[r][q * 4 + 0] = f.x; tile[r][q * 4 + 1] = f.y;
      tile[r][q * 4 + 2] = f.z; tile[r][q * 4 + 3] = f.w;
    }
    __syncthreads();
    {
      int dr = t >> 3, c2 = t & 7;
      bf16x4 u;
#pragma unroll
      for (int j = 0; j < 4; ++j) u[j] = (__bf16)tile[c2 * 4 + j][dr];
      // sigma: swap kv bits 2,3 == swap c2 bits 0,1 (4-group moves intact)
      int c2s = (c2 & 4) | ((c2 & 1) << 1) | ((c2 >> 1) & 1);
      *(bf16x4*)(VTb + ((size_t)(b * DH + d0 + dr)) * S_LEN + s0 + c2s * 4) = u;
    }
  } else if (bid < 4096) {  // Q f32 -> bf16 * QSCALE flat
    size_t i = ((size_t)(bid - 3072) * 256 + t) * 8;
    float4 a = *(const float4*)(Q + i), b = *(const float4*)(Q + i + 4);
    a.x *= QSCALE; a.y *= QSCALE; a.z *= QSCALE; a.w *= QSCALE;
    b.x *= QSCALE; b.y *= QSCALE; b.z *= QSCALE; b.w *= QSCALE;
    *(bf16x8*)(Qb + i) = pack8(a, b);
  } else {  // w transposes via 32x32 LDS tiles (coalesced both sides)
    const int bw = bid - 4096;
    if (bw < 64) {  // w1 [128][512] f32 -> w1t[n][k]=w1[k][n] (512x128 bf16)
      const int tr = bw >> 4, tc = bw & 15;  // 4 x 16 tiles
      const int r0 = tr * 32, c0 = tc * 32;
      {
        int row = t >> 3, q = t & 7;
        float4 f = *(const float4*)(w1 + (size_t)(r0 + row) * 512 + c0 + q * 4);
        tile[row][q * 4 + 0] = f.x; tile[row][q * 4 + 1] = f.y;
        tile[row][q * 4 + 2] = f.z; tile[row][q * 4 + 3] = f.w;
      }
      __syncthreads();
      {
        int dr = t >> 3, c2 = t & 7;
        bf16x4 u;
#pragma unroll
        for (int j = 0; j < 4; ++j) u[j] = (__bf16)tile[c2 * 4 + j][dr];
        *(bf16x4*)(w1t + (size_t)(c0 + dr) * 128 + r0 + c2 * 4) = u;
      }
    } else {  // w2 [512][128] f32 -> w2t[n][k]=w2[k][n] (128x512 bf16)
      const int bw2 = bw - 64;
      const int tr = bw2 >> 2, tc = bw2 & 3;  // 16 x 4 tiles
      const int r0 = tr * 32, c0 = tc * 32;
      {
        int row = t >> 3, q = t & 7;
        float4 f = *(const float4*)(w2 + (size_t)(r0 + row) * 128 + c0 + q * 4);
        tile[row][q * 4 + 0] = f.x; tile[row][q * 4 + 1] = f.y;
        tile[row][q * 4 + 2] = f.z; tile[row][q * 4 + 3] = f.w;
      }
      __syncthreads();
      {
        int dr = t >> 3, c2 = t & 7;
        bf16x4 u;
#pragma unroll
        for (int j = 0; j < 4; ++j) u[j] = (__bf16)tile[c2 * 4 + j][dr];
        *(bf16x4*)(w2t + (size_t)(c0 + dr) * 512 + r0 + c2 * 4) = u;
      }
    }
  }
}

// ---------------------------------------------------------------------------
// Flash attention, kv-split. 32x32 swapped MFMA (R6/R14/R17/R19-verified):
//   S^T = K · Q^T  -> lane owns q = l&31;  O^T = V^T · P^T.
// No-max softmax, per-lane lsum; sigma-permuted V -> lane-local P.
// Q pre-converted (bf16, QSCALE folded). NEW: T5 setprio around MFMA
// clusters (2 independent blocks/CU -> scheduler has phases to arbitrate).
// Block = 4 waves (256 thr), 128 q-rows (32/wave). LDS 64 KB -> 2 blocks/CU.
// ---------------------------------------------------------------------------
template <int NSP>
__global__ __launch_bounds__(256, 2) void attn_fa(
    const __bf16* __restrict__ Qb, const __bf16* __restrict__ Kb,
    const __bf16* __restrict__ VTb, __bf16* __restrict__ Op,
    float* __restrict__ lbuf) {
  constexpr int NTT = (S_LEN / NSP) / 64;
  __shared__ __attribute__((aligned(16))) __bf16 kl[2][64 * 128];  // 32 KB
  __shared__ __attribute__((aligned(16))) __bf16 vt[2][128 * 64];  // 32 KB

  const int tid = threadIdx.x;
  const int w = tid >> 6, l = tid & 63;
  const int q5 = l & 31, hi = l >> 5;
  const int bid = blockIdx.x;
  const int split = bid % NSP;
  const int qt = (bid / NSP) % 32;
  const int b = bid / (NSP * 32);
  const int R = b * S_LEN + qt * 128 + w * 32 + q5;
  const int kv0 = split * (S_LEN / NSP);

  // Q^T B-frags: lane holds Q[q5-row][kc*16 + hi*8 + j] (pre-scaled bf16)
  bf16x8 qf[8];
  {
    const __bf16* qp = Qb + (size_t)R * DH + hi * 8;
#pragma unroll
    for (int kc = 0; kc < 8; ++kc) qf[kc] = *(const bf16x8*)(qp + kc * 16);
  }

  f32x16 o[4];
#pragma unroll
  for (int db = 0; db < 4; ++db) o[db] = f32x16{};
  float lsum = 0.f;

  const __bf16* kbase = Kb + (size_t)b * S_LEN * DH;
  const __bf16* vbase = VTb + (size_t)b * DH * S_LEN;

  // R6-verified 4-wave staging: wave w stages K rows [w*16,w*16+16) and
  // VT rows [w*32,w*32+32). LDS image: slot[r][c] = src[r][c ^ ((r&7)<<3)].
#define STAGE(BUF, S_OFF)                                                      \
  {                                                                            \
    _Pragma("unroll") for (int i = 0; i < 4; ++i) {                            \
      int r = w * 16 + i * 4 + (l >> 4);                                       \
      gl16(kbase + (size_t)((S_OFF) + r) * DH + (((l & 15) * 8) ^ ((r & 7) << 3)), \
           &kl[BUF][(w * 16 + i * 4) * 128]);                                  \
    }                                                                          \
    _Pragma("unroll") for (int i = 0; i < 4; ++i) {                            \
      int d = w * 32 + i * 8 + (l >> 3);                                       \
      gl16(vbase + (size_t)d * S_LEN + (S_OFF) + (((l & 7) * 8) ^ ((d & 7) << 3)), \
           &vt[BUF][(w * 32 + i * 8) * 64]);                                   \
    }                                                                          \
  }

  STAGE(0, kv0);
  __syncthreads();  // implicit vmcnt(0) drain -> buffer 0 ready

  const int swz = (q5 & 7) << 3;

  int cur = 0;
  for (int t = 0; t < NTT; ++t) {
    if (t + 1 < NTT) STAGE(cur ^ 1, kv0 + (t + 1) * 64);  // prefetch in flight

    // ---- QK^T (S^T) + softmax + lane-local P assembly (R14-verified) ----
    bf16x8 pb[4];  // pb[kvb*2+kc2] feeds PV k-range 16*(2kvb+kc2)+8hi+j
#pragma unroll
    for (int kvb = 0; kvb < 2; ++kvb) {
      f32x16 acc = f32x16{};
      const int row = kvb * 32 + q5;  // row&7 == q5&7
      __builtin_amdgcn_s_setprio(1);
#pragma unroll
      for (int kc = 0; kc < 8; ++kc) {
        bf16x8 kf = *(const bf16x8*)&kl[cur][(row * 128 + kc * 16 + hi * 8) ^ swz];
        acc = MFMA32(kf, qf[kc], acc);
      }
      __builtin_amdgcn_s_setprio(0);
      // p = exp2(s); pack quads (4 consecutive kv) as 2x u32 of bf16 pairs.
      unsigned pk[4][2];
#pragma unroll
      for (int t4 = 0; t4 < 4; ++t4) {
        float e0 = fexp2(acc[4 * t4 + 0]), e1 = fexp2(acc[4 * t4 + 1]);
        float e2 = fexp2(acc[4 * t4 + 2]), e3 = fexp2(acc[4 * t4 + 3]);
        lsum += (e0 + e1) + (e2 + e3);
        pk[t4][0] = packbf(e0, e1);
        pk[t4][1] = packbf(e2, e3);
      }
#pragma unroll
      for (int kc2 = 0; kc2 < 2; ++kc2) {
        union { unsigned u[4]; bf16x8 v; } uu;
        uu.u[0] = pk[2 * kc2][0];
        uu.u[1] = pk[2 * kc2][1];
        uu.u[2] = pk[2 * kc2 + 1][0];
        uu.u[3] = pk[2 * kc2 + 1][1];
        pb[kvb * 2 + kc2] = uu.v;
      }
    }

    // ---- PV: O^T[d][q] += V^T·P^T (sigma in data) ----
    __builtin_amdgcn_s_setprio(1);
#pragma unroll
    for (int db = 0; db < 4; ++db) {
      const int row = db * 32 + q5;  // row&7 == q5&7
#pragma unroll
      for (int kc = 0; kc < 4; ++kc) {
        bf16x8 vf = *(const bf16x8*)&vt[cur][(row * 64 + kc * 16 + hi * 8) ^ swz];
        o[db] = MFMA32(vf, pb[kc], o[db]);
      }
    }
    __builtin_amdgcn_s_setprio(0);

    __syncthreads();  // drains prefetch (hidden under compute) + buffer swap
    cur ^= 1;
  }
#undef STAGE

  // ---- epilogue (R6-verified): full-row l, write O/l + l ----
  lsum += __shfl_xor(lsum, 32);
  const float inv = 1.f / lsum;
  __bf16* orow = Op + ((size_t)split * NR + R) * DH;
#pragma unroll
  for (int db = 0; db < 4; ++db)
#pragma unroll
    for (int t4 = 0; t4 < 4; ++t4) {
      bf16x4 pk;
#pragma unroll
      for (int qi = 0; qi < 4; ++qi) pk[qi] = (__bf16)(o[db][4 * t4 + qi] * inv);
      *(bf16x4*)(orow + db * 32 + t4 * 8 + hi * 4) = pk;
    }
  if (hi == 0) lbuf[(size_t)split * NR + R] = lsum;
}

// ---------------------------------------------------------------------------
// Fused: combine kv-splits + LN1 (LDS only) + FFN + LN2 -> Out.
// 32 rows per block (2 x 16-row groups) — R17-verified form (f32 residual).
// ---------------------------------------------------------------------------
template <int NSP>
__global__ __launch_bounds__(256) void ffn_fused(
    const __bf16* __restrict__ Op, const float* __restrict__ lbuf,
    const float* __restrict__ g1, const float* __restrict__ be1,
    const __bf16* __restrict__ w1t, const __bf16* __restrict__ w2t,
    const float* __restrict__ b1, const float* __restrict__ b2,
    const float* __restrict__ g2, const float* __restrict__ be2,
    float* __restrict__ Out) {
  __shared__ __attribute__((aligned(16))) __bf16 xl[2][16 * 128];  // 8 KB
  __shared__ float xr[2][16][132];                                 // 16.5 KB
  __shared__ __attribute__((aligned(16))) __bf16 hl[16 * 512];     // 16 KB
  __shared__ float part[4][16][2];

  const int tid = threadIdx.x;
  const int w = tid >> 6, l = tid & 63, lg = l >> 4, lc = l & 15;
  const int row0 = blockIdx.x * 32;

  // ---- phase 1: combine splits + LayerNorm1 for BOTH 16-row groups ----
#pragma unroll
  for (int g = 0; g < 2; ++g) {
    const int prow = tid >> 4, pc8 = tid & 15;
    const int R = row0 + g * 16 + prow;
    float v[8] = {0.f, 0.f, 0.f, 0.f, 0.f, 0.f, 0.f, 0.f};
    float den = 0.f;
#pragma unroll
    for (int s = 0; s < NSP; ++s) {
      float ls = lbuf[(size_t)s * NR + R];
      den += ls;
      bf16x8 p = *(const bf16x8*)(Op + ((size_t)s * NR + R) * DH + pc8 * 8);
#pragma unroll
      for (int j = 0; j < 8; ++j) v[j] += ls * (float)p[j];
    }
    float inv = 1.f / den;
    float sm = 0.f, sq = 0.f;
#pragma unroll
    for (int j = 0; j < 8; ++j) {
      v[j] *= inv;
      sm += v[j];
      sq += v[j] * v[j];
    }
#pragma unroll
    for (int d = 1; d < 16; d <<= 1) {
      sm += __shfl_xor(sm, d);
      sq += __shfl_xor(sq, d);
    }
    float mu = sm * (1.f / 128.f);
    float var = sq * (1.f / 128.f) - mu * mu;
    float rs = rsqrtf(var + 1e-5f);
    float4 ga = *(const float4*)(g1 + pc8 * 8), gb = *(const float4*)(g1 + pc8 * 8 + 4);
    float4 ba = *(const float4*)(be1 + pc8 * 8), bb = *(const float4*)(be1 + pc8 * 8 + 4);
    float gv[8] = {ga.x, ga.y, ga.z, ga.w, gb.x, gb.y, gb.z, gb.w};
    float bv[8] = {ba.x, ba.y, ba.z, ba.w, bb.x, bb.y, bb.z, bb.w};
    bf16x8 xb;
    float xo[8];
#pragma unroll
    for (int j = 0; j < 8; ++j) {
      xo[j] = (v[j] - mu) * rs * gv[j] + bv[j];
      xb[j] = (__bf16)xo[j];
    }
    *(bf16x8*)&xl[g][(prow * 128 + pc8 * 8) ^ ((prow & 7) << 3)] = xb;
    *(float4*)&xr[g][prow][pc8 * 8] = make_float4(xo[0], xo[1], xo[2], xo[3]);
    *(float4*)&xr[g][prow][pc8 * 8 + 4] = make_float4(xo[4], xo[5], xo[6], xo[7]);
  }
  __syncthreads();

  // ---- per group: GEMM1 -> hl -> GEMM2 + residual + LN2 -> Out ----
  for (int g = 0; g < 2; ++g) {
    // GEMM1 + bias + relu -> hl
    bf16x8 xf[4];
    const int m = lc;
#pragma unroll
    for (int kc = 0; kc < 4; ++kc)
      xf[kc] = *(const bf16x8*)&xl[g][(m * 128 + kc * 32 + lg * 8) ^ ((m & 7) << 3)];

#pragma unroll
    for (int nb = 0; nb < 8; ++nb) {
      int n0 = w * 128 + nb * 16 + lc;
      const __bf16* wp = w1t + (size_t)n0 * 128 + lg * 8;
      f32x4 acc = (f32x4){0.f, 0.f, 0.f, 0.f};
#pragma unroll
      for (int kc = 0; kc < 4; ++kc)
        acc = MFMA16(xf[kc], *(const bf16x8*)(wp + kc * 32), acc);
      float bias = b1[n0];
#pragma unroll
      for (int r = 0; r < 4; ++r) {
        int rr = lg * 4 + r;
        hl[rr * 512 + (n0 ^ (lg << 4))] = (__bf16)fmaxf(acc[r] + bias, 0.f);
      }
    }
    __syncthreads();

    // GEMM2 (K=512) + bias + residual + LN2
    const int col0 = w * 32 + lc;
    f32x4 oo[2];
#pragma unroll
    for (int nb2 = 0; nb2 < 2; ++nb2) {
      int d0 = col0 + nb2 * 16;
      const __bf16* wp2 = w2t + (size_t)d0 * 512 + lg * 8;
      f32x4 acc = (f32x4){0.f, 0.f, 0.f, 0.f};
#pragma unroll
      for (int kc = 0; kc < 16; ++kc) {
        bf16x8 ha = *(const bf16x8*)&hl[lc * 512 + ((kc * 32 + lg * 8) ^ ((lc >> 2) << 4))];
        acc = MFMA16(ha, *(const bf16x8*)(wp2 + kc * 32), acc);
      }
      oo[nb2] = acc;
    }

    float b2v[2] = {b2[col0], b2[col0 + 16]};
    float g2v[2] = {g2[col0], g2[col0 + 16]};
    float be2v[2] = {be2[col0], be2[col0 + 16]};
    float sum[4] = {0.f, 0.f, 0.f, 0.f}, sq[4] = {0.f, 0.f, 0.f, 0.f};
#pragma unroll
    for (int nb2 = 0; nb2 < 2; ++nb2)
#pragma unroll
      for (int r = 0; r < 4; ++r) {
        int rr = lg * 4 + r;
        float xv = xr[g][rr][col0 + nb2 * 16];
        float tv = oo[nb2][r] + b2v[nb2] + xv;
        oo[nb2][r] = tv;
        sum[r] += tv;
        sq[r] += tv * tv;
      }
#pragma unroll
    for (int r = 0; r < 4; ++r) {
#pragma unroll
      for (int d = 1; d < 16; d <<= 1) {
        sum[r] += __shfl_xor(sum[r], d);
        sq[r] += __shfl_xor(sq[r], d);
      }
      if (lc == 0) {
        part[w][lg * 4 + r][0] = sum[r];
        part[w][lg * 4 + r][1] = sq[r];
      }
    }
    __syncthreads();

#pragma unroll
    for (int r = 0; r < 4; ++r) {
      int rr = lg * 4 + r;
      float S = 0.f, Qq = 0.f;
#pragma unroll
      for (int ww = 0; ww < 4; ++ww) {
        S += part[ww][rr][0];
        Qq += part[ww][rr][1];
      }
      float mu = S * (1.f / 128.f);
      float var = Qq * (1.f / 128.f) - mu * mu;
      float rs = rsqrtf(var + 1e-5f);
#pragma unroll
      for (int nb2 = 0; nb2 < 2; ++nb2)
        Out[(size_t)(row0 + g * 16 + rr) * DH + col0 + nb2 * 16] =
            (oo[nb2][r] - mu) * rs * g2v[nb2] + be2v[nb2];
    }
    __syncthreads();  // hl/part free for next group
  }
}

// ---------------------------------------------------------------------------
extern "C" void kernel_launch(void* const* d_in, const int* in_sizes, int n_in,
                              void* d_out, int out_size, void* d_ws, size_t ws_size,
                              hipStream_t stream) {
  const float* Q = (const float*)d_in[0];
  const float* K = (const float*)d_in[1];
  const float* V = (const float*)d_in[2];
  const float* w1 = (const float*)d_in[3];
  const float* b1 = (const float*)d_in[4];
  const float* w2 = (const float*)d_in[5];
  const float* b2 = (const float*)d_in[6];
  const float* g1 = (const float*)d_in[7];
  const float* be1 = (const float*)d_in[8];
  const float* g2 = (const float*)d_in[9];
  const float* be2 = (const float*)d_in[10];
  float* Out = (float*)d_out;

  char* p = (char*)d_ws;
  __bf16* w1t = (__bf16*)p;  p += 512 * 128 * 2;
  __bf16* w2t = (__bf16*)p;  p += 128 * 512 * 2;
  __bf16* Kb  = (__bf16*)p;  p += (size_t)NR * DH * 2;
  __bf16* VTb = (__bf16*)p;  p += (size_t)NR * DH * 2;
  __bf16* Qb  = (__bf16*)p;  p += (size_t)NR * DH * 2;
  float* lbuf = (float*)p;   p += (size_t)4 * NR * 4;
  __bf16* Op  = (__bf16*)p;  // 4 * NR * DH * 2 = 16 MB

  prep_all<<<4224, 256, 0, stream>>>(K, V, Q, w1, w2, Kb, VTb, Qb, w1t, w2t);
  // NSP=4: grid 512 = exactly 2 blocks/CU on 256 CUs, one dispatch round.
  attn_fa<4><<<4 * 32 * 4, 256, 0, stream>>>(Qb, Kb, VTb, Op, lbuf);
  ffn_fused<4><<<NR / 32, 256, 0, stream>>>(Op, lbuf, g1, be1, w1t, w2t, b1,
                                            b2, g2, be2, Out);
}

// Round 21
// 84.321 us; speedup vs baseline: 1.0337x; 1.0231x over previous
//
#include <hip/hip_runtime.h>
#include <hip/hip_bf16.h>

typedef __attribute__((ext_vector_type(8))) __bf16 bf16x8;
typedef __attribute__((ext_vector_type(4))) __bf16 bf16x4;
typedef __attribute__((ext_vector_type(4))) float f32x4;
typedef __attribute__((ext_vector_type(16))) float f32x16;

#define MFMA16(a, b, c) __builtin_amdgcn_mfma_f32_16x16x32_bf16((a), (b), (c), 0, 0, 0)
#define MFMA32(a, b, c) __builtin_amdgcn_mfma_f32_32x32x16_bf16((a), (b), (c), 0, 0, 0)

static constexpr int S_LEN = 4096;
static constexpr int DH = 128;
static constexpr int NR = 4 * S_LEN;  // B*S = 16384
// 1/sqrt(128) * log2(e): fold softmax scale AND exp->exp2 conversion into Q
static constexpr float QSCALE = 0.12752551286084110f;

__device__ inline bf16x8 pack8(float4 a, float4 b) {
  bf16x8 r;
  r[0] = (__bf16)a.x; r[1] = (__bf16)a.y; r[2] = (__bf16)a.z; r[3] = (__bf16)a.w;
  r[4] = (__bf16)b.x; r[5] = (__bf16)b.y; r[6] = (__bf16)b.z; r[7] = (__bf16)b.w;
  return r;
}

__device__ __forceinline__ float fexp2(float x) {
#if __has_builtin(__builtin_amdgcn_exp2f)
  return __builtin_amdgcn_exp2f(x);
#else
  return exp2f(x);
#endif
}

// Pack two f32 -> u32 of 2 bf16: a -> low 16 (elem 0), b -> high (elem 1).
// HW-verified in R10/R12/R14.
__device__ __forceinline__ unsigned packbf(float a, float b) {
  union { __bf16 h[2]; unsigned u; } t;
  t.h[0] = (__bf16)a;
  t.h[1] = (__bf16)b;
  return t.u;
}

typedef __attribute__((address_space(1))) const unsigned GU32;
typedef __attribute__((address_space(3))) unsigned LU32;
// async global->LDS, 16B per lane; LDS dest = wave-uniform base + lane*16
__device__ __forceinline__ void gl16(const void* g, void* s) {
  __builtin_amdgcn_global_load_lds((GU32*)g, (LU32*)s, 16, 0, 0);
}

// ---------------------------------------------------------------------------
// One prep kernel (R20-verified): conv K->bf16 | transpose V -> VT bf16
// (sigma: kv bits 2,3 swapped — R14-verified) | conv Q->bf16*QSCALE |
// transpose w1,w2 via coalesced 32x32 LDS tiles.
// grid = 1024 + 2048 + 1024 + 128 = 4224 blocks x 256 thr.
// ---------------------------------------------------------------------------
__global__ __launch_bounds__(256) void prep_all(
    const float* __restrict__ K, const float* __restrict__ V,
    const float* __restrict__ Q, const float* __restrict__ w1,
    const float* __restrict__ w2, __bf16* __restrict__ Kb,
    __bf16* __restrict__ VTb, __bf16* __restrict__ Qb,
    __bf16* __restrict__ w1t, __bf16* __restrict__ w2t) {
  __shared__ float tile[32][33];
  const int bid = blockIdx.x;
  const int t = threadIdx.x;
  if (bid < 1024) {  // K f32 -> bf16 flat
    size_t i = ((size_t)bid * 256 + t) * 8;
    float4 a = *(const float4*)(K + i), b = *(const float4*)(K + i + 4);
    *(bf16x8*)(Kb + i) = pack8(a, b);
  } else if (bid < 3072) {  // V [B][S][128] -> VT [B][128][S] via 32x32 tiles
    const int bid2 = bid - 1024;
    const int b = bid2 >> 9, rem = bid2 & 511;
    const int s0 = (rem >> 2) * 32, d0 = (rem & 3) * 32;
    {
      int r = t >> 3, q = t & 7;
      float4 f = *(const float4*)(V + ((size_t)(b * S_LEN + s0 + r)) * DH + d0 + q * 4);
      tile[r][q * 4 + 0] = f.x; tile[r][q * 4 + 1] = f.y;
      tile[r][q * 4 + 2] = f.z; tile[r][q * 4 + 3] = f.w;
    }
    __syncthreads();
    {
      int dr = t >> 3, c2 = t & 7;
      bf16x4 u;
#pragma unroll
      for (int j = 0; j < 4; ++j) u[j] = (__bf16)tile[c2 * 4 + j][dr];
      // sigma: swap kv bits 2,3 == swap c2 bits 0,1 (4-group moves intact)
      int c2s = (c2 & 4) | ((c2 & 1) << 1) | ((c2 >> 1) & 1);
      *(bf16x4*)(VTb + ((size_t)(b * DH + d0 + dr)) * S_LEN + s0 + c2s * 4) = u;
    }
  } else if (bid < 4096) {  // Q f32 -> bf16 * QSCALE flat
    size_t i = ((size_t)(bid - 3072) * 256 + t) * 8;
    float4 a = *(const float4*)(Q + i), b = *(const float4*)(Q + i + 4);
    a.x *= QSCALE; a.y *= QSCALE; a.z *= QSCALE; a.w *= QSCALE;
    b.x *= QSCALE; b.y *= QSCALE; b.z *= QSCALE; b.w *= QSCALE;
    *(bf16x8*)(Qb + i) = pack8(a, b);
  } else {  // w transposes via 32x32 LDS tiles (coalesced both sides)
    const int bw = bid - 4096;
    if (bw < 64) {  // w1 [128][512] f32 -> w1t[n][k]=w1[k][n] (512x128 bf16)
      const int tr = bw >> 4, tc = bw & 15;  // 4 x 16 tiles
      const int r0 = tr * 32, c0 = tc * 32;
      {
        int row = t >> 3, q = t & 7;
        float4 f = *(const float4*)(w1 + (size_t)(r0 + row) * 512 + c0 + q * 4);
        tile[row][q * 4 + 0] = f.x; tile[row][q * 4 + 1] = f.y;
        tile[row][q * 4 + 2] = f.z; tile[row][q * 4 + 3] = f.w;
      }
      __syncthreads();
      {
        int dr = t >> 3, c2 = t & 7;
        bf16x4 u;
#pragma unroll
        for (int j = 0; j < 4; ++j) u[j] = (__bf16)tile[c2 * 4 + j][dr];
        *(bf16x4*)(w1t + (size_t)(c0 + dr) * 128 + r0 + c2 * 4) = u;
      }
    } else {  // w2 [512][128] f32 -> w2t[n][k]=w2[k][n] (128x512 bf16)
      const int bw2 = bw - 64;
      const int tr = bw2 >> 2, tc = bw2 & 3;  // 16 x 4 tiles
      const int r0 = tr * 32, c0 = tc * 32;
      {
        int row = t >> 3, q = t & 7;
        float4 f = *(const float4*)(w2 + (size_t)(r0 + row) * 128 + c0 + q * 4);
        tile[row][q * 4 + 0] = f.x; tile[row][q * 4 + 1] = f.y;
        tile[row][q * 4 + 2] = f.z; tile[row][q * 4 + 3] = f.w;
      }
      __syncthreads();
      {
        int dr = t >> 3, c2 = t & 7;
        bf16x4 u;
#pragma unroll
        for (int j = 0; j < 4; ++j) u[j] = (__bf16)tile[c2 * 4 + j][dr];
        *(bf16x4*)(w2t + (size_t)(c0 + dr) * 512 + r0 + c2 * 4) = u;
      }
    }
  }
}

// ---------------------------------------------------------------------------
// Flash attention, kv-split. 32x32 swapped MFMA — VERBATIM R19 (benched
// 46.4 us; setprio removed again after R20 showed it costs ~2 us here):
//   S^T = K · Q^T  -> lane owns q = l&31;  O^T = V^T · P^T.
// No-max softmax, per-lane lsum; sigma-permuted V -> lane-local P.
// Q pre-converted (bf16, QSCALE folded) -> 8x16B prologue loads.
// Block = 4 waves (256 thr), 128 q-rows (32/wave). LDS 64 KB -> 2 blocks/CU.
// ---------------------------------------------------------------------------
template <int NSP>
__global__ __launch_bounds__(256, 2) void attn_fa(
    const __bf16* __restrict__ Qb, const __bf16* __restrict__ Kb,
    const __bf16* __restrict__ VTb, __bf16* __restrict__ Op,
    float* __restrict__ lbuf) {
  constexpr int NTT = (S_LEN / NSP) / 64;
  __shared__ __attribute__((aligned(16))) __bf16 kl[2][64 * 128];  // 32 KB
  __shared__ __attribute__((aligned(16))) __bf16 vt[2][128 * 64];  // 32 KB

  const int tid = threadIdx.x;
  const int w = tid >> 6, l = tid & 63;
  const int q5 = l & 31, hi = l >> 5;
  const int bid = blockIdx.x;
  const int split = bid % NSP;
  const int qt = (bid / NSP) % 32;
  const int b = bid / (NSP * 32);
  const int R = b * S_LEN + qt * 128 + w * 32 + q5;
  const int kv0 = split * (S_LEN / NSP);

  // Q^T B-frags: lane holds Q[q5-row][kc*16 + hi*8 + j] (pre-scaled bf16)
  bf16x8 qf[8];
  {
    const __bf16* qp = Qb + (size_t)R * DH + hi * 8;
#pragma unroll
    for (int kc = 0; kc < 8; ++kc) qf[kc] = *(const bf16x8*)(qp + kc * 16);
  }

  f32x16 o[4];
#pragma unroll
  for (int db = 0; db < 4; ++db) o[db] = f32x16{};
  float lsum = 0.f;

  const __bf16* kbase = Kb + (size_t)b * S_LEN * DH;
  const __bf16* vbase = VTb + (size_t)b * DH * S_LEN;

  // R6-verified 4-wave staging: wave w stages K rows [w*16,w*16+16) and
  // VT rows [w*32,w*32+32). LDS image: slot[r][c] = src[r][c ^ ((r&7)<<3)].
#define STAGE(BUF, S_OFF)                                                      \
  {                                                                            \
    _Pragma("unroll") for (int i = 0; i < 4; ++i) {                            \
      int r = w * 16 + i * 4 + (l >> 4);                                       \
      gl16(kbase + (size_t)((S_OFF) + r) * DH + (((l & 15) * 8) ^ ((r & 7) << 3)), \
           &kl[BUF][(w * 16 + i * 4) * 128]);                                  \
    }                                                                          \
    _Pragma("unroll") for (int i = 0; i < 4; ++i) {                            \
      int d = w * 32 + i * 8 + (l >> 3);                                       \
      gl16(vbase + (size_t)d * S_LEN + (S_OFF) + (((l & 7) * 8) ^ ((d & 7) << 3)), \
           &vt[BUF][(w * 32 + i * 8) * 64]);                                   \
    }                                                                          \
  }

  STAGE(0, kv0);
  __syncthreads();  // implicit vmcnt(0) drain -> buffer 0 ready

  const int swz = (q5 & 7) << 3;

  int cur = 0;
  for (int t = 0; t < NTT; ++t) {
    if (t + 1 < NTT) STAGE(cur ^ 1, kv0 + (t + 1) * 64);  // prefetch in flight

    // ---- QK^T (S^T) + softmax + lane-local P assembly (R14-verified) ----
    bf16x8 pb[4];  // pb[kvb*2+kc2] feeds PV k-range 16*(2kvb+kc2)+8hi+j
#pragma unroll
    for (int kvb = 0; kvb < 2; ++kvb) {
      f32x16 acc = f32x16{};
      const int row = kvb * 32 + q5;  // row&7 == q5&7
#pragma unroll
      for (int kc = 0; kc < 8; ++kc) {
        bf16x8 kf = *(const bf16x8*)&kl[cur][(row * 128 + kc * 16 + hi * 8) ^ swz];
        acc = MFMA32(kf, qf[kc], acc);
      }
      // p = exp2(s); pack quads (4 consecutive kv) as 2x u32 of bf16 pairs.
      unsigned pk[4][2];
#pragma unroll
      for (int t4 = 0; t4 < 4; ++t4) {
        float e0 = fexp2(acc[4 * t4 + 0]), e1 = fexp2(acc[4 * t4 + 1]);
        float e2 = fexp2(acc[4 * t4 + 2]), e3 = fexp2(acc[4 * t4 + 3]);
        lsum += (e0 + e1) + (e2 + e3);
        pk[t4][0] = packbf(e0, e1);
        pk[t4][1] = packbf(e2, e3);
      }
#pragma unroll
      for (int kc2 = 0; kc2 < 2; ++kc2) {
        union { unsigned u[4]; bf16x8 v; } uu;
        uu.u[0] = pk[2 * kc2][0];
        uu.u[1] = pk[2 * kc2][1];
        uu.u[2] = pk[2 * kc2 + 1][0];
        uu.u[3] = pk[2 * kc2 + 1][1];
        pb[kvb * 2 + kc2] = uu.v;
      }
    }

    // ---- PV: O^T[d][q] += V^T·P^T (sigma in data) ----
#pragma unroll
    for (int db = 0; db < 4; ++db) {
      const int row = db * 32 + q5;  // row&7 == q5&7
#pragma unroll
      for (int kc = 0; kc < 4; ++kc) {
        bf16x8 vf = *(const bf16x8*)&vt[cur][(row * 64 + kc * 16 + hi * 8) ^ swz];
        o[db] = MFMA32(vf, pb[kc], o[db]);
      }
    }

    __syncthreads();  // drains prefetch (hidden under compute) + buffer swap
    cur ^= 1;
  }
#undef STAGE

  // ---- epilogue (R6-verified): full-row l, write O/l + l ----
  lsum += __shfl_xor(lsum, 32);
  const float inv = 1.f / lsum;
  __bf16* orow = Op + ((size_t)split * NR + R) * DH;
#pragma unroll
  for (int db = 0; db < 4; ++db)
#pragma unroll
    for (int t4 = 0; t4 < 4; ++t4) {
      bf16x4 pk;
#pragma unroll
      for (int qi = 0; qi < 4; ++qi) pk[qi] = (__bf16)(o[db][4 * t4 + qi] * inv);
      *(bf16x4*)(orow + db * 32 + t4 * 8 + hi * 4) = pk;
    }
  if (hi == 0) lbuf[(size_t)split * NR + R] = lsum;
}

// ---------------------------------------------------------------------------
// Fused: combine kv-splits + LN1 (LDS only) + FFN + LN2 -> Out.
// 32 rows per block (2 x 16-row groups) — R17-verified form (f32 residual).
// ---------------------------------------------------------------------------
template <int NSP>
__global__ __launch_bounds__(256) void ffn_fused(
    const __bf16* __restrict__ Op, const float* __restrict__ lbuf,
    const float* __restrict__ g1, const float* __restrict__ be1,
    const __bf16* __restrict__ w1t, const __bf16* __restrict__ w2t,
    const float* __restrict__ b1, const float* __restrict__ b2,
    const float* __restrict__ g2, const float* __restrict__ be2,
    float* __restrict__ Out) {
  __shared__ __attribute__((aligned(16))) __bf16 xl[2][16 * 128];  // 8 KB
  __shared__ float xr[2][16][132];                                 // 16.5 KB
  __shared__ __attribute__((aligned(16))) __bf16 hl[16 * 512];     // 16 KB
  __shared__ float part[4][16][2];

  const int tid = threadIdx.x;
  const int w = tid >> 6, l = tid & 63, lg = l >> 4, lc = l & 15;
  const int row0 = blockIdx.x * 32;

  // ---- phase 1: combine splits + LayerNorm1 for BOTH 16-row groups ----
#pragma unroll
  for (int g = 0; g < 2; ++g) {
    const int prow = tid >> 4, pc8 = tid & 15;
    const int R = row0 + g * 16 + prow;
    float v[8] = {0.f, 0.f, 0.f, 0.f, 0.f, 0.f, 0.f, 0.f};
    float den = 0.f;
#pragma unroll
    for (int s = 0; s < NSP; ++s) {
      float ls = lbuf[(size_t)s * NR + R];
      den += ls;
      bf16x8 p = *(const bf16x8*)(Op + ((size_t)s * NR + R) * DH + pc8 * 8);
#pragma unroll
      for (int j = 0; j < 8; ++j) v[j] += ls * (float)p[j];
    }
    float inv = 1.f / den;
    float sm = 0.f, sq = 0.f;
#pragma unroll
    for (int j = 0; j < 8; ++j) {
      v[j] *= inv;
      sm += v[j];
      sq += v[j] * v[j];
    }
#pragma unroll
    for (int d = 1; d < 16; d <<= 1) {
      sm += __shfl_xor(sm, d);
      sq += __shfl_xor(sq, d);
    }
    float mu = sm * (1.f / 128.f);
    float var = sq * (1.f / 128.f) - mu * mu;
    float rs = rsqrtf(var + 1e-5f);
    float4 ga = *(const float4*)(g1 + pc8 * 8), gb = *(const float4*)(g1 + pc8 * 8 + 4);
    float4 ba = *(const float4*)(be1 + pc8 * 8), bb = *(const float4*)(be1 + pc8 * 8 + 4);
    float gv[8] = {ga.x, ga.y, ga.z, ga.w, gb.x, gb.y, gb.z, gb.w};
    float bv[8] = {ba.x, ba.y, ba.z, ba.w, bb.x, bb.y, bb.z, bb.w};
    bf16x8 xb;
    float xo[8];
#pragma unroll
    for (int j = 0; j < 8; ++j) {
      xo[j] = (v[j] - mu) * rs * gv[j] + bv[j];
      xb[j] = (__bf16)xo[j];
    }
    *(bf16x8*)&xl[g][(prow * 128 + pc8 * 8) ^ ((prow & 7) << 3)] = xb;
    *(float4*)&xr[g][prow][pc8 * 8] = make_float4(xo[0], xo[1], xo[2], xo[3]);
    *(float4*)&xr[g][prow][pc8 * 8 + 4] = make_float4(xo[4], xo[5], xo[6], xo[7]);
  }
  __syncthreads();

  // ---- per group: GEMM1 -> hl -> GEMM2 + residual + LN2 -> Out ----
  for (int g = 0; g < 2; ++g) {
    // GEMM1 + bias + relu -> hl
    bf16x8 xf[4];
    const int m = lc;
#pragma unroll
    for (int kc = 0; kc < 4; ++kc)
      xf[kc] = *(const bf16x8*)&xl[g][(m * 128 + kc * 32 + lg * 8) ^ ((m & 7) << 3)];

#pragma unroll
    for (int nb = 0; nb < 8; ++nb) {
      int n0 = w * 128 + nb * 16 + lc;
      const __bf16* wp = w1t + (size_t)n0 * 128 + lg * 8;
      f32x4 acc = (f32x4){0.f, 0.f, 0.f, 0.f};
#pragma unroll
      for (int kc = 0; kc < 4; ++kc)
        acc = MFMA16(xf[kc], *(const bf16x8*)(wp + kc * 32), acc);
      float bias = b1[n0];
#pragma unroll
      for (int r = 0; r < 4; ++r) {
        int rr = lg * 4 + r;
        hl[rr * 512 + (n0 ^ (lg << 4))] = (__bf16)fmaxf(acc[r] + bias, 0.f);
      }
    }
    __syncthreads();

    // GEMM2 (K=512) + bias + residual + LN2
    const int col0 = w * 32 + lc;
    f32x4 oo[2];
#pragma unroll
    for (int nb2 = 0; nb2 < 2; ++nb2) {
      int d0 = col0 + nb2 * 16;
      const __bf16* wp2 = w2t + (size_t)d0 * 512 + lg * 8;
      f32x4 acc = (f32x4){0.f, 0.f, 0.f, 0.f};
#pragma unroll
      for (int kc = 0; kc < 16; ++kc) {
        bf16x8 ha = *(const bf16x8*)&hl[lc * 512 + ((kc * 32 + lg * 8) ^ ((lc >> 2) << 4))];
        acc = MFMA16(ha, *(const bf16x8*)(wp2 + kc * 32), acc);
      }
      oo[nb2] = acc;
    }

    float b2v[2] = {b2[col0], b2[col0 + 16]};
    float g2v[2] = {g2[col0], g2[col0 + 16]};
    float be2v[2] = {be2[col0], be2[col0 + 16]};
    float sum[4] = {0.f, 0.f, 0.f, 0.f}, sq[4] = {0.f, 0.f, 0.f, 0.f};
#pragma unroll
    for (int nb2 = 0; nb2 < 2; ++nb2)
#pragma unroll
      for (int r = 0; r < 4; ++r) {
        int rr = lg * 4 + r;
        float xv = xr[g][rr][col0 + nb2 * 16];
        float tv = oo[nb2][r] + b2v[nb2] + xv;
        oo[nb2][r] = tv;
        sum[r] += tv;
        sq[r] += tv * tv;
      }
#pragma unroll
    for (int r = 0; r < 4; ++r) {
#pragma unroll
      for (int d = 1; d < 16; d <<= 1) {
        sum[r] += __shfl_xor(sum[r], d);
        sq[r] += __shfl_xor(sq[r], d);
      }
      if (lc == 0) {
        part[w][lg * 4 + r][0] = sum[r];
        part[w][lg * 4 + r][1] = sq[r];
      }
    }
    __syncthreads();

#pragma unroll
    for (int r = 0; r < 4; ++r) {
      int rr = lg * 4 + r;
      float S = 0.f, Qq = 0.f;
#pragma unroll
      for (int ww = 0; ww < 4; ++ww) {
        S += part[ww][rr][0];
        Qq += part[ww][rr][1];
      }
      float mu = S * (1.f / 128.f);
      float var = Qq * (1.f / 128.f) - mu * mu;
      float rs = rsqrtf(var + 1e-5f);
#pragma unroll
      for (int nb2 = 0; nb2 < 2; ++nb2)
        Out[(size_t)(row0 + g * 16 + rr) * DH + col0 + nb2 * 16] =
            (oo[nb2][r] - mu) * rs * g2v[nb2] + be2v[nb2];
    }
    __syncthreads();  // hl/part free for next group
  }
}

// ---------------------------------------------------------------------------
extern "C" void kernel_launch(void* const* d_in, const int* in_sizes, int n_in,
                              void* d_out, int out_size, void* d_ws, size_t ws_size,
                              hipStream_t stream) {
  const float* Q = (const float*)d_in[0];
  const float* K = (const float*)d_in[1];
  const float* V = (const float*)d_in[2];
  const float* w1 = (const float*)d_in[3];
  const float* b1 = (const float*)d_in[4];
  const float* w2 = (const float*)d_in[5];
  const float* b2 = (const float*)d_in[6];
  const float* g1 = (const float*)d_in[7];
  const float* be1 = (const float*)d_in[8];
  const float* g2 = (const float*)d_in[9];
  const float* be2 = (const float*)d_in[10];
  float* Out = (float*)d_out;

  char* p = (char*)d_ws;
  __bf16* w1t = (__bf16*)p;  p += 512 * 128 * 2;
  __bf16* w2t = (__bf16*)p;  p += 128 * 512 * 2;
  __bf16* Kb  = (__bf16*)p;  p += (size_t)NR * DH * 2;
  __bf16* VTb = (__bf16*)p;  p += (size_t)NR * DH * 2;
  __bf16* Qb  = (__bf16*)p;  p += (size_t)NR * DH * 2;
  float* lbuf = (float*)p;   p += (size_t)4 * NR * 4;
  __bf16* Op  = (__bf16*)p;  // 4 * NR * DH * 2 = 16 MB

  prep_all<<<4224, 256, 0, stream>>>(K, V, Q, w1, w2, Kb, VTb, Qb, w1t, w2t);
  // NSP=4: grid 512 = exactly 2 blocks/CU on 256 CUs, one dispatch round.
  attn_fa<4><<<4 * 32 * 4, 256, 0, stream>>>(Qb, Kb, VTb, Op, lbuf);
  ffn_fused<4><<<NR / 32, 256, 0, stream>>>(Op, lbuf, g1, be1, w1t, w2t, b1,
                                            b2, g2, be2, Out);
}